// Round 4
// baseline (349.291 us; speedup 1.0000x reference)
//
#include <hip/hip_runtime.h>
#include <hip/hip_bf16.h>

#define D  128
#define KN 32

typedef __attribute__((ext_vector_type(8))) short bf16x8;
typedef __attribute__((ext_vector_type(4))) float f32x4;

static __device__ __forceinline__ unsigned short f2bf(float f) {
    union { float f; unsigned int u; } v; v.f = f;
    unsigned int u = v.u;
    u += 0x7fff + ((u >> 16) & 1);   // round-to-nearest-even
    return (unsigned short)(u >> 16);
}
static __device__ __forceinline__ float bf2f(unsigned short h) {
    union { float f; unsigned int u; } v; v.u = ((unsigned int)h) << 16;
    return v.f;
}
static __device__ __forceinline__ float bflo(unsigned int u) {
    union { float f; unsigned int u; } v; v.u = u << 16; return v.f;
}
static __device__ __forceinline__ float bfhi(unsigned int u) {
    union { float f; unsigned int u; } v; v.u = u & 0xffff0000u; return v.f;
}

// One-shot: transpose+convert W1 halves and W2 into bf16 [col][k] layouts.
__global__ __launch_bounds__(256) void wt_kernel(
    const float* __restrict__ W1, const float* __restrict__ W2,
    unsigned short* __restrict__ W1Tt, unsigned short* __restrict__ W1Tb,
    unsigned short* __restrict__ W2T)
{
    int idx = blockIdx.x * 256 + threadIdx.x;
    if (idx < D * D) {
        int col = idx >> 7, e = idx & 127;
        W1Tt[col * D + e] = f2bf(W1[e * D + col]);
        W1Tb[col * D + e] = f2bf(W1[(D + e) * D + col]);
        W2T [col * D + e] = f2bf(W2[e * D + col]);
    }
}

// Fused P1/Q producer. Zero LDS, zero barriers: each wave owns 32 rows,
// A-frags built in-register from coalesced fp32 loads, B-frags from the
// L1-resident 32KB transposed weight. Blocks [0,nvBlocks): P1 = emb@W1top
// (also emits bf16 emb copy EB). Blocks [nvBlocks,..): Q = emb[vnodes]@W1bot+b1.
__global__ __launch_bounds__(256) void p1q_kernel(
    const float* __restrict__ emb, const int* __restrict__ vnodes,
    int NV, int NN, int nvBlocks,
    const unsigned short* __restrict__ W1Tt, const unsigned short* __restrict__ W1Tb,
    const float* __restrict__ b1,
    unsigned short* __restrict__ P1, unsigned short* __restrict__ Q,
    unsigned short* __restrict__ EB)
{
    const int tid  = threadIdx.x;
    const int lane = tid & 63;
    const int w    = tid >> 6;
    const int m    = lane & 15, q = lane >> 4;

    const bool nv = (int)blockIdx.x < nvBlocks;
    const int  bi = nv ? blockIdx.x : blockIdx.x - nvBlocks;
    const int  M  = nv ? NV : NN;
    const unsigned short* WT = nv ? W1Tt : W1Tb;
    unsigned short* dst = nv ? P1 : Q;
    const int r0w = bi * 128 + w * 32;

    int row[2], vr[2];
#pragma unroll
    for (int mt = 0; mt < 2; ++mt) {
        int r = r0w + 16 * mt + m;
        row[mt] = r < M ? r : M - 1;
        vr[mt]  = nv ? row[mt] : vnodes[row[mt]];
    }

    f32x4 acc[2][8];
#pragma unroll
    for (int mt = 0; mt < 2; ++mt)
#pragma unroll
        for (int nt = 0; nt < 8; ++nt) acc[mt][nt] = (f32x4){0.f, 0.f, 0.f, 0.f};

#pragma unroll
    for (int kk = 0; kk < 4; ++kk) {
        bf16x8 a[2];
#pragma unroll
        for (int mt = 0; mt < 2; ++mt) {
            const float* src = emb + (long)vr[mt] * D + kk * 32 + q * 8;
            float4 f0 = *(const float4*)src;
            float4 f1 = *(const float4*)(src + 4);
            a[mt][0] = (short)f2bf(f0.x); a[mt][1] = (short)f2bf(f0.y);
            a[mt][2] = (short)f2bf(f0.z); a[mt][3] = (short)f2bf(f0.w);
            a[mt][4] = (short)f2bf(f1.x); a[mt][5] = (short)f2bf(f1.y);
            a[mt][6] = (short)f2bf(f1.z); a[mt][7] = (short)f2bf(f1.w);
            if (nv && EB)   // bf16 emb copy for the aggregation gather
                *(bf16x8*)(EB + (long)row[mt] * D + kk * 32 + q * 8) = a[mt];
        }
#pragma unroll
        for (int nt = 0; nt < 8; ++nt) {
            bf16x8 b = *(const bf16x8*)(WT + (16 * nt + m) * D + kk * 32 + q * 8);
            acc[0][nt] = __builtin_amdgcn_mfma_f32_16x16x32_bf16(a[0], b, acc[0][nt], 0, 0, 0);
            acc[1][nt] = __builtin_amdgcn_mfma_f32_16x16x32_bf16(a[1], b, acc[1][nt], 0, 0, 0);
        }
    }

    float bv[8];
#pragma unroll
    for (int nt = 0; nt < 8; ++nt) bv[nt] = nv ? 0.f : b1[16 * nt + m];

    // C/D layout: col = 16*nt + (lane&15), row = 16*mt + 4*(lane>>4) + r
#pragma unroll
    for (int mt = 0; mt < 2; ++mt)
#pragma unroll
        for (int nt = 0; nt < 8; ++nt)
#pragma unroll
            for (int r = 0; r < 4; ++r) {
                int orow = r0w + 16 * mt + 4 * q + r;
                if (orow < M)
                    dst[(long)orow * D + 16 * nt + m] = f2bf(acc[mt][nt][r] + bv[nt]);
            }
}

// Wave-per-node aggregator. Zero LDS, zero barriers. One wave computes
// h2 = relu(relu(P1[idx]+Q[nd]) @ W2 + b2) for its node's 32 neighbors
// (64 MFMAs), scores via W3 + shuffle-reduce, softmax in-register, then
// the prefetched bf16 EB gather is combined with att weights.
__global__ __launch_bounds__(256) void agg_kernel(
    const unsigned short* __restrict__ EB, const int* __restrict__ nidx,
    const unsigned short* __restrict__ W2T, const float* __restrict__ b2,
    const float* __restrict__ W3,
    const unsigned short* __restrict__ P1, const unsigned short* __restrict__ Q,
    float* __restrict__ out, int NN)
{
    const int lane = threadIdx.x & 63;
    const int w    = threadIdx.x >> 6;
    const int m    = lane & 15, q = lane >> 4;
    const int nd   = blockIdx.x * 4 + w;
    if (nd >= NN) return;

    const int idxv = nidx[nd * KN + (lane & 31)];
    const int r0 = __shfl(idxv, m);        // neighbor row for mt=0
    const int r1 = __shfl(idxv, 16 + m);   // neighbor row for mt=1

    // prefetch aggregation gather: lane owns cols {2*lane, 2*lane+1}
    unsigned int ek[KN];
#pragma unroll
    for (int k = 0; k < KN; ++k) {
        int ik = __shfl(idxv, k);
        ek[k] = *(const unsigned int*)(EB + (long)ik * D + lane * 2);
    }

    float b2v[8], w3v[8];
#pragma unroll
    for (int nt = 0; nt < 8; ++nt) {
        b2v[nt] = b2[16 * nt + m];
        w3v[nt] = W3[16 * nt + m];
    }

    f32x4 acc[2][8];
#pragma unroll
    for (int mt = 0; mt < 2; ++mt)
#pragma unroll
        for (int nt = 0; nt < 8; ++nt) acc[mt][nt] = (f32x4){0.f, 0.f, 0.f, 0.f};

#pragma unroll
    for (int kk = 0; kk < 4; ++kk) {
        bf16x8 qv = *(const bf16x8*)(Q  + (long)nd * D + kk * 32 + q * 8);
        bf16x8 p0 = *(const bf16x8*)(P1 + (long)r0 * D + kk * 32 + q * 8);
        bf16x8 p1 = *(const bf16x8*)(P1 + (long)r1 * D + kk * 32 + q * 8);
        bf16x8 a0, a1;
#pragma unroll
        for (int h = 0; h < 8; ++h) {
            float v0 = bf2f((unsigned short)p0[h]) + bf2f((unsigned short)qv[h]);
            float v1 = bf2f((unsigned short)p1[h]) + bf2f((unsigned short)qv[h]);
            a0[h] = (short)f2bf(v0 > 0.f ? v0 : 0.f);
            a1[h] = (short)f2bf(v1 > 0.f ? v1 : 0.f);
        }
#pragma unroll
        for (int nt = 0; nt < 8; ++nt) {
            bf16x8 b = *(const bf16x8*)(W2T + (16 * nt + m) * D + kk * 32 + q * 8);
            acc[0][nt] = __builtin_amdgcn_mfma_f32_16x16x32_bf16(a0, b, acc[0][nt], 0, 0, 0);
            acc[1][nt] = __builtin_amdgcn_mfma_f32_16x16x32_bf16(a1, b, acc[1][nt], 0, 0, 0);
        }
    }

    // scores: relu(h2 + b2) . W3, reduced over the 16 col-lanes (m)
    float att[2][4];
#pragma unroll
    for (int mt = 0; mt < 2; ++mt)
#pragma unroll
        for (int r = 0; r < 4; ++r) {
            float p = 0.f;
#pragma unroll
            for (int nt = 0; nt < 8; ++nt) {
                float h = acc[mt][nt][r] + b2v[nt];
                p += (h > 0.f ? h : 0.f) * w3v[nt];
            }
            att[mt][r] = p;
        }
#pragma unroll
    for (int off = 1; off <= 8; off <<= 1)
#pragma unroll
        for (int mt = 0; mt < 2; ++mt)
#pragma unroll
            for (int r = 0; r < 4; ++r)
                att[mt][r] += __shfl_xor(att[mt][r], off);

    // softmax over 32 scores (8 in-lane values x 4 quads); b3 cancels.
    float mx = att[0][0];
#pragma unroll
    for (int mt = 0; mt < 2; ++mt)
#pragma unroll
        for (int r = 0; r < 4; ++r) mx = fmaxf(mx, att[mt][r]);
    mx = fmaxf(mx, __shfl_xor(mx, 16));
    mx = fmaxf(mx, __shfl_xor(mx, 32));
    float sum = 0.f;
#pragma unroll
    for (int mt = 0; mt < 2; ++mt)
#pragma unroll
        for (int r = 0; r < 4; ++r) {
            att[mt][r] = __expf(att[mt][r] - mx);
            sum += att[mt][r];
        }
    sum += __shfl_xor(sum, 16);
    sum += __shfl_xor(sum, 32);
    const float inv = 1.f / sum;
#pragma unroll
    for (int mt = 0; mt < 2; ++mt)
#pragma unroll
        for (int r = 0; r < 4; ++r) att[mt][r] *= inv;

    // aggregation: row k's att lives at quad (k>>2)&3, register [k>>4][k&3]
    float ox = 0.f, oy = 0.f;
#pragma unroll
    for (int k = 0; k < KN; ++k) {
        float a = __shfl(att[k >> 4][k & 3], ((k >> 2) & 3) << 4);
        ox += a * bflo(ek[k]);
        oy += a * bfhi(ek[k]);
    }
    float2 o = {ox, oy};
    *(float2*)(out + (long)nd * D + lane * 2) = o;
}

// Correct-but-slow fp32 VALU fallback (only if ws is too small).
__global__ __launch_bounds__(128) void naive_kernel(
    const float* __restrict__ emb, const int* __restrict__ vnodes,
    const int* __restrict__ nidx,
    const float* __restrict__ W1, const float* __restrict__ b1,
    const float* __restrict__ W2, const float* __restrict__ b2,
    const float* __restrict__ W3, const float* __restrict__ b3,
    float* __restrict__ out)
{
    __shared__ float sE[KN + 1][D];
    __shared__ float sH[KN][D];
    __shared__ float sH2[KN][D];
    __shared__ float sS[KN];
    __shared__ float sA2[KN];
    const int node = blockIdx.x, tid = threadIdx.x;

    for (int r = 0; r < KN + 1; ++r) {
        int vr = (r < KN) ? nidx[node * KN + r] : vnodes[node];
        sE[r][tid] = emb[(long)vr * D + tid];
    }
    __syncthreads();
    for (int k = 0; k < KN; ++k) {
        float s = b1[tid];
        for (int e = 0; e < D; ++e) s += sE[k][e]  * W1[e * D + tid];
        for (int e = 0; e < D; ++e) s += sE[KN][e] * W1[(D + e) * D + tid];
        sH[k][tid] = s > 0.f ? s : 0.f;
    }
    __syncthreads();
    for (int k = 0; k < KN; ++k) {
        float s = b2[tid];
        for (int e = 0; e < D; ++e) s += sH[k][e] * W2[e * D + tid];
        sH2[k][tid] = s > 0.f ? s : 0.f;
    }
    __syncthreads();
    if (tid < KN) {
        float s = b3[0];
        for (int e = 0; e < D; ++e) s += sH2[tid][e] * W3[e];
        sS[tid] = s;
    }
    __syncthreads();
    if (tid == 0) {
        float mx = sS[0];
        for (int k = 1; k < KN; ++k) mx = fmaxf(mx, sS[k]);
        float sum = 0.f;
        for (int k = 0; k < KN; ++k) { sA2[k] = __expf(sS[k] - mx); sum += sA2[k]; }
        for (int k = 0; k < KN; ++k) sA2[k] /= sum;
    }
    __syncthreads();
    float a = 0.f;
    for (int k = 0; k < KN; ++k) a += sA2[k] * sE[k][tid];
    out[(long)node * D + tid] = a;
}

extern "C" void kernel_launch(void* const* d_in, const int* in_sizes, int n_in,
                              void* d_out, int out_size, void* d_ws, size_t ws_size,
                              hipStream_t stream) {
    const float* emb    = (const float*)d_in[0];
    const int*   vnodes = (const int*)d_in[1];
    const int*   nidx   = (const int*)d_in[2];
    const float* W1     = (const float*)d_in[3];
    const float* b1     = (const float*)d_in[4];
    const float* W2     = (const float*)d_in[5];
    const float* b2     = (const float*)d_in[6];
    const float* W3     = (const float*)d_in[7];
    const float* b3     = (const float*)d_in[8];
    float* out = (float*)d_out;

    const int NV = in_sizes[0] / D;   // 200000
    const int NN = in_sizes[1];       // 20000

    const size_t p1_elems = (size_t)NV * D;
    const size_t q_elems  = (size_t)NN * D;
    const size_t wt_elems = (size_t)D * D;
    const size_t need = (2 * p1_elems + q_elems + 3 * wt_elems) * sizeof(unsigned short);

    if (ws_size >= need) {
        unsigned short* P1   = (unsigned short*)d_ws;
        unsigned short* Q    = P1 + p1_elems;
        unsigned short* W1Tt = Q + q_elems;
        unsigned short* W1Tb = W1Tt + wt_elems;
        unsigned short* W2T  = W1Tb + wt_elems;
        unsigned short* EB   = W2T + wt_elems;

        const int nvBlocks = (NV + 127) / 128;
        const int qBlocks  = (NN + 127) / 128;

        wt_kernel<<<(D * D + 255) / 256, 256, 0, stream>>>(W1, W2, W1Tt, W1Tb, W2T);
        p1q_kernel<<<nvBlocks + qBlocks, 256, 0, stream>>>(
            emb, vnodes, NV, NN, nvBlocks, W1Tt, W1Tb, b1, P1, Q, EB);
        agg_kernel<<<(NN + 3) / 4, 256, 0, stream>>>(
            EB, nidx, W2T, b2, W3, P1, Q, out, NN);
    } else {
        naive_kernel<<<NN, D, 0, stream>>>(emb, vnodes, nidx, W1, b1, W2, b2, W3, b3, out);
    }
}

// Round 5
// 303.173 us; speedup vs baseline: 1.1521x; 1.1521x over previous
//
#include <hip/hip_runtime.h>
#include <hip/hip_bf16.h>

#define D  128
#define KN 32

typedef __attribute__((ext_vector_type(8))) short bf16x8;
typedef __attribute__((ext_vector_type(4))) float f32x4;

static __device__ __forceinline__ unsigned short f2bf(float f) {
    union { float f; unsigned int u; } v; v.f = f;
    unsigned int u = v.u;
    u += 0x7fff + ((u >> 16) & 1);   // round-to-nearest-even
    return (unsigned short)(u >> 16);
}
static __device__ __forceinline__ float bf2f(unsigned short h) {
    union { float f; unsigned int u; } v; v.u = ((unsigned int)h) << 16;
    return v.f;
}

// One-shot: transpose+convert W1 halves and W2 into bf16 [col][k] layouts.
__global__ __launch_bounds__(256) void wt_kernel(
    const float* __restrict__ W1, const float* __restrict__ W2,
    unsigned short* __restrict__ W1Tt, unsigned short* __restrict__ W1Tb,
    unsigned short* __restrict__ W2T)
{
    int idx = blockIdx.x * 256 + threadIdx.x;
    if (idx < D * D) {
        int col = idx >> 7, e = idx & 127;
        W1Tt[col * D + e] = f2bf(W1[e * D + col]);
        W1Tb[col * D + e] = f2bf(W1[(D + e) * D + col]);
        W2T [col * D + e] = f2bf(W2[e * D + col]);
    }
}

// Fused P1/Q producer, R3-style LDS-staged A (coalesced), reg-resident B.
// Blocks [0,nvBlocks): P1 = emb@W1top (+ bf16 emb copy EB).
// Blocks [nvBlocks,..): Q = emb[vnodes]@W1bot + b1.
__global__ __launch_bounds__(256) void p1q_kernel(
    const float* __restrict__ emb, const int* __restrict__ vnodes,
    int NV, int NN, int nvBlocks,
    const unsigned short* __restrict__ W1Tt, const unsigned short* __restrict__ W1Tb,
    const float* __restrict__ b1,
    unsigned short* __restrict__ P1, unsigned short* __restrict__ Q,
    unsigned short* __restrict__ EB)
{
    __shared__ unsigned short sA[128][136];

    const int tid  = threadIdx.x;
    const int lane = tid & 63;
    const int w    = tid >> 6;
    const int m    = lane & 15, q = lane >> 4;

    const bool nv = (int)blockIdx.x < nvBlocks;
    const int  bi = nv ? blockIdx.x : blockIdx.x - nvBlocks;
    const int  M  = nv ? NV : NN;
    const unsigned short* WT = nv ? W1Tt : W1Tb;
    unsigned short* dst = nv ? P1 : Q;
    const int r0 = bi * 128;

    // stage 128 rows fp32->bf16 (coalesced float4 stream / gather)
#pragma unroll
    for (int i = 0; i < 16; ++i) {
        int e = tid + 256 * i;
        int row = e >> 5, c4 = (e & 31) << 2;
        int r = r0 + row; if (r > M - 1) r = M - 1;
        int vr = nv ? r : vnodes[r];
        const float4 f = *(const float4*)(emb + (long)vr * D + c4);
        ushort4 h;
        h.x = f2bf(f.x); h.y = f2bf(f.y); h.z = f2bf(f.z); h.w = f2bf(f.w);
        *(ushort4*)(&sA[row][c4]) = h;
    }
    __syncthreads();

    // fused bf16-emb emission (identity pass only), coalesced from LDS
    if (nv) {
        int row = tid >> 1, half = tid & 1;
        if (r0 + row < M) {
#pragma unroll
            for (int j = 0; j < 8; ++j)
                *(bf16x8*)(EB + (long)(r0 + row) * D + half * 64 + j * 8) =
                    *(const bf16x8*)(&sA[row][half * 64 + j * 8]);
        }
    }

    bf16x8 Bf[2][4];
#pragma unroll
    for (int nt = 0; nt < 2; ++nt)
#pragma unroll
        for (int kk = 0; kk < 4; ++kk)
            Bf[nt][kk] = *(const bf16x8*)(WT + (32 * w + 16 * nt + m) * D + kk * 32 + q * 8);
    float bv[2];
#pragma unroll
    for (int nt = 0; nt < 2; ++nt) bv[nt] = nv ? 0.f : b1[32 * w + 16 * nt + m];

    f32x4 acc[8][2];
#pragma unroll
    for (int mt = 0; mt < 8; ++mt)
#pragma unroll
        for (int nt = 0; nt < 2; ++nt) acc[mt][nt] = (f32x4){0.f, 0.f, 0.f, 0.f};

#pragma unroll
    for (int kk = 0; kk < 4; ++kk) {
#pragma unroll
        for (int mt = 0; mt < 8; ++mt) {
            bf16x8 a = *(const bf16x8*)(&sA[16 * mt + m][kk * 32 + q * 8]);
            acc[mt][0] = __builtin_amdgcn_mfma_f32_16x16x32_bf16(a, Bf[0][kk], acc[mt][0], 0, 0, 0);
            acc[mt][1] = __builtin_amdgcn_mfma_f32_16x16x32_bf16(a, Bf[1][kk], acc[mt][1], 0, 0, 0);
        }
    }

    // C/D layout: col=lane&15, row=(lane>>4)*4+reg
#pragma unroll
    for (int mt = 0; mt < 8; ++mt)
#pragma unroll
        for (int nt = 0; nt < 2; ++nt) {
            int col = 32 * w + 16 * nt + m;
#pragma unroll
            for (int r = 0; r < 4; ++r) {
                int row = r0 + 16 * mt + 4 * q + r;
                if (row < M) dst[(long)row * D + col] = f2bf(acc[mt][nt][r] + bv[nt]);
            }
        }
}

// Fused per-node aggregator, software-pipelined: while group g runs
// MFMA/score/softmax/aggregate, the P1 rows of group g+gridDim are already
// in flight into registers (pf). 4 nodes/group, 3 barriers/iter.
__global__ __launch_bounds__(256, 2) void agg_kernel(
    const unsigned short* __restrict__ EB, const int* __restrict__ nidx,
    const unsigned short* __restrict__ W2T, const float* __restrict__ b2,
    const float* __restrict__ W3, const float* __restrict__ b3,
    const unsigned short* __restrict__ P1, const unsigned short* __restrict__ Q,
    float* __restrict__ out, int NN)
{
    __shared__ unsigned short sX[128][136];
    __shared__ int   sIdx[128];
    __shared__ float sSp[4][128];
    __shared__ float sAtt[128];

    const int tid  = threadIdx.x;
    const int lane = tid & 63;
    const int w    = tid >> 6;          // wave index == node sub-index
    const int m    = lane & 15, q = lane >> 4;
    const int row  = tid >> 1, half = tid & 1;   // staging role: 2 threads/row

    // register-resident B fragments (W2T), per-wave 32-col slice
    bf16x8 Bf[2][4];
#pragma unroll
    for (int nt = 0; nt < 2; ++nt)
#pragma unroll
        for (int kk = 0; kk < 4; ++kk)
            Bf[nt][kk] = *(const bf16x8*)(W2T + (32 * w + 16 * nt + m) * D + kk * 32 + q * 8);
    float b2v[2], w3v[2];
#pragma unroll
    for (int nt = 0; nt < 2; ++nt) {
        int col = 32 * w + 16 * nt + m;
        b2v[nt] = b2[col];
        w3v[nt] = W3[col];
    }
    const float b3s = b3[0];

    const int groups = (NN + 3) >> 2;

    // ---- pipeline prologue: group blockIdx.x ----
    int g = blockIdx.x;
    int ni_cur = 0;
    bf16x8 pf[8];
    if (g < groups) {
        int nd = g * 4 + (row >> 5); if (nd > NN - 1) nd = NN - 1;
        ni_cur = nidx[nd * KN + (row & 31)];
#pragma unroll
        for (int j = 0; j < 8; ++j)
            pf[j] = *(const bf16x8*)(P1 + (long)ni_cur * D + half * 64 + j * 8);
    }

    for (; g < groups; g += gridDim.x) {
        const int node0 = g * 4;
        int nd = node0 + (row >> 5); if (nd > NN - 1) nd = NN - 1;

        // ---- convert+store X = relu(pf + Q[nd]) ----
        if (half == 0) sIdx[row] = ni_cur;
        {
            const bf16x8* qq = (const bf16x8*)(Q + (long)nd * D) + half * 8;
#pragma unroll
            for (int j = 0; j < 8; ++j) {
                bf16x8 qv = qq[j], r;
#pragma unroll
                for (int h = 0; h < 8; ++h) {
                    float v = bf2f((unsigned short)pf[j][h]) + bf2f((unsigned short)qv[h]);
                    r[h] = (short)f2bf(v > 0.f ? v : 0.f);
                }
                *(bf16x8*)(&sX[row][half * 64 + j * 8]) = r;
            }
        }

        // next-group index load (issue before barrier; independent)
        const int gn = g + gridDim.x;
        const bool more = gn < groups;
        int ni_next = ni_cur;
        if (more) {
            int ndn = gn * 4 + (row >> 5); if (ndn > NN - 1) ndn = NN - 1;
            ni_next = nidx[ndn * KN + (row & 31)];
        }
        __syncthreads();

        // ---- EB prefetch for current group (needs sIdx) ----
        bf16x8 gv[8];
#pragma unroll
        for (int j = 0; j < 8; ++j) {
            int k = (lane >> 4) + 4 * j;
            int ik = sIdx[w * KN + k];
            gv[j] = *(const bf16x8*)(EB + (long)ik * D + (lane & 15) * 8);
        }

        // ---- P1 prefetch for NEXT group (in flight during compute) ----
        if (more) {
#pragma unroll
            for (int j = 0; j < 8; ++j)
                pf[j] = *(const bf16x8*)(P1 + (long)ni_next * D + half * 64 + j * 8);
        }

        // ---- layer-2 GEMM: 8 M-tiles x this wave's 2 N-tiles ----
        f32x4 acc[8][2];
#pragma unroll
        for (int mt = 0; mt < 8; ++mt)
#pragma unroll
            for (int nt = 0; nt < 2; ++nt) acc[mt][nt] = (f32x4){0.f, 0.f, 0.f, 0.f};

#pragma unroll
        for (int kk = 0; kk < 4; ++kk) {
#pragma unroll
            for (int mt = 0; mt < 8; ++mt) {
                bf16x8 a = *(const bf16x8*)(&sX[16 * mt + m][kk * 32 + q * 8]);
                acc[mt][0] = __builtin_amdgcn_mfma_f32_16x16x32_bf16(a, Bf[0][kk], acc[mt][0], 0, 0, 0);
                acc[mt][1] = __builtin_amdgcn_mfma_f32_16x16x32_bf16(a, Bf[1][kk], acc[mt][1], 0, 0, 0);
            }
        }

        // ---- relu+bias, dot W3, reduce across 16 col-lanes ----
#pragma unroll
        for (int mt = 0; mt < 8; ++mt) {
            float p[4];
#pragma unroll
            for (int r = 0; r < 4; ++r) {
                float h0 = acc[mt][0][r] + b2v[0]; h0 = h0 > 0.f ? h0 : 0.f;
                float h1 = acc[mt][1][r] + b2v[1]; h1 = h1 > 0.f ? h1 : 0.f;
                p[r] = h0 * w3v[0] + h1 * w3v[1];
            }
#pragma unroll
            for (int off = 8; off >= 1; off >>= 1)
#pragma unroll
                for (int r = 0; r < 4; ++r) p[r] += __shfl_xor(p[r], off, 16);
            if (m == 0) {
#pragma unroll
                for (int r = 0; r < 4; ++r) sSp[w][16 * mt + 4 * q + r] = p[r];
            }
        }
        __syncthreads();

        // ---- softmax: 128 scores = 4 nodes x 32 neighbors ----
        if (tid < 128) {
            float s = sSp[0][tid] + sSp[1][tid] + sSp[2][tid] + sSp[3][tid] + b3s;
            float mx = s;
#pragma unroll
            for (int off = 16; off >= 1; off >>= 1) mx = fmaxf(mx, __shfl_xor(mx, off, 32));
            float e = __expf(s - mx);
            float sum = e;
#pragma unroll
            for (int off = 16; off >= 1; off >>= 1) sum += __shfl_xor(sum, off, 32);
            sAtt[tid] = e / sum;
        }
        __syncthreads();

        // ---- aggregation: node w per wave, from prefetched gv ----
        {
            float r[8] = {0.f, 0.f, 0.f, 0.f, 0.f, 0.f, 0.f, 0.f};
#pragma unroll
            for (int j = 0; j < 8; ++j) {
                float a = sAtt[w * KN + (lane >> 4) + 4 * j];
#pragma unroll
                for (int h = 0; h < 8; ++h)
                    r[h] += a * bf2f((unsigned short)gv[j][h]);
            }
#pragma unroll
            for (int h = 0; h < 8; ++h) {
                r[h] += __shfl_xor(r[h], 16);
                r[h] += __shfl_xor(r[h], 32);
            }
            int ndw = node0 + w;
            if (lane < 16 && ndw < NN) {
                float4 o0 = {r[0], r[1], r[2], r[3]};
                float4 o1 = {r[4], r[5], r[6], r[7]};
                *(float4*)(out + (long)ndw * D + lane * 8)     = o0;
                *(float4*)(out + (long)ndw * D + lane * 8 + 4) = o1;
            }
        }
        // no 4th barrier needed: next write to sX/sIdx happens after the
        // convert phase, which follows this iteration's barriers; sAtt's
        // next write is 2 barriers away.
        ni_cur = ni_next;
    }
}

// Correct-but-slow fp32 VALU fallback (only if ws is too small).
__global__ __launch_bounds__(128) void naive_kernel(
    const float* __restrict__ emb, const int* __restrict__ vnodes,
    const int* __restrict__ nidx,
    const float* __restrict__ W1, const float* __restrict__ b1,
    const float* __restrict__ W2, const float* __restrict__ b2,
    const float* __restrict__ W3, const float* __restrict__ b3,
    float* __restrict__ out)
{
    __shared__ float sE[KN + 1][D];
    __shared__ float sH[KN][D];
    __shared__ float sH2[KN][D];
    __shared__ float sS[KN];
    __shared__ float sA2[KN];
    const int node = blockIdx.x, tid = threadIdx.x;

    for (int r = 0; r < KN + 1; ++r) {
        int vr = (r < KN) ? nidx[node * KN + r] : vnodes[node];
        sE[r][tid] = emb[(long)vr * D + tid];
    }
    __syncthreads();
    for (int k = 0; k < KN; ++k) {
        float s = b1[tid];
        for (int e = 0; e < D; ++e) s += sE[k][e]  * W1[e * D + tid];
        for (int e = 0; e < D; ++e) s += sE[KN][e] * W1[(D + e) * D + tid];
        sH[k][tid] = s > 0.f ? s : 0.f;
    }
    __syncthreads();
    for (int k = 0; k < KN; ++k) {
        float s = b2[tid];
        for (int e = 0; e < D; ++e) s += sH[k][e] * W2[e * D + tid];
        sH2[k][tid] = s > 0.f ? s : 0.f;
    }
    __syncthreads();
    if (tid < KN) {
        float s = b3[0];
        for (int e = 0; e < D; ++e) s += sH2[tid][e] * W3[e];
        sS[tid] = s;
    }
    __syncthreads();
    if (tid == 0) {
        float mx = sS[0];
        for (int k = 1; k < KN; ++k) mx = fmaxf(mx, sS[k]);
        float sum = 0.f;
        for (int k = 0; k < KN; ++k) { sA2[k] = __expf(sS[k] - mx); sum += sA2[k]; }
        for (int k = 0; k < KN; ++k) sA2[k] /= sum;
    }
    __syncthreads();
    float a = 0.f;
    for (int k = 0; k < KN; ++k) a += sA2[k] * sE[k][tid];
    out[(long)node * D + tid] = a;
}

extern "C" void kernel_launch(void* const* d_in, const int* in_sizes, int n_in,
                              void* d_out, int out_size, void* d_ws, size_t ws_size,
                              hipStream_t stream) {
    const float* emb    = (const float*)d_in[0];
    const int*   vnodes = (const int*)d_in[1];
    const int*   nidx   = (const int*)d_in[2];
    const float* W1     = (const float*)d_in[3];
    const float* b1     = (const float*)d_in[4];
    const float* W2     = (const float*)d_in[5];
    const float* b2     = (const float*)d_in[6];
    const float* W3     = (const float*)d_in[7];
    const float* b3     = (const float*)d_in[8];
    float* out = (float*)d_out;

    const int NV = in_sizes[0] / D;   // 200000
    const int NN = in_sizes[1];       // 20000

    const size_t p1_elems = (size_t)NV * D;
    const size_t q_elems  = (size_t)NN * D;
    const size_t wt_elems = (size_t)D * D;
    const size_t need = (2 * p1_elems + q_elems + 3 * wt_elems) * sizeof(unsigned short);

    if (ws_size >= need) {
        unsigned short* P1   = (unsigned short*)d_ws;
        unsigned short* Q    = P1 + p1_elems;
        unsigned short* W1Tt = Q + q_elems;
        unsigned short* W1Tb = W1Tt + wt_elems;
        unsigned short* W2T  = W1Tb + wt_elems;
        unsigned short* EB   = W2T + wt_elems;

        const int nvBlocks = (NV + 127) / 128;
        const int qBlocks  = (NN + 127) / 128;

        wt_kernel<<<(D * D + 255) / 256, 256, 0, stream>>>(W1, W2, W1Tt, W1Tb, W2T);
        p1q_kernel<<<nvBlocks + qBlocks, 256, 0, stream>>>(
            emb, vnodes, NV, NN, nvBlocks, W1Tt, W1Tb, b1, P1, Q, EB);
        agg_kernel<<<1024, 256, 0, stream>>>(
            EB, nidx, W2T, b2, W3, b3, P1, Q, out, NN);
    } else {
        naive_kernel<<<NN, D, 0, stream>>>(emb, vnodes, nidx, W1, b1, W2, b2, W3, b3, out);
    }
}